// Round 6
// baseline (1329.946 us; speedup 1.0000x reference)
//
#include <hip/hip_runtime.h>
#include <math.h>

#define BATCH 512
#define TT    1024
#define FF    128
#define UU    50
#define ZN    200          // 4*UU
#define NP    208          // padded N (13 * 16)
#define NT    13           // N tiles of 16
#define MROWS (BATCH * TT) // 524288
#define BM    128          // rows per GEMM block
#define RPP   8            // rows per pass in fallback GEMM
#define RSTRIDE 52         // Rt row stride in floats (208 B, conflict-free b128)
#define ESTRIDE 212        // GEMM epilogue LDS row stride (2-way max on dump)

typedef __attribute__((ext_vector_type(8))) short bhalf8;
typedef __attribute__((ext_vector_type(4))) short bhalf4;
typedef __attribute__((ext_vector_type(4))) float f32x4;

__device__ __forceinline__ float sigmoid_fast(float x) {
    return 1.0f / (1.0f + __expf(-x));
}
__device__ __forceinline__ float tanh_fast(float x) {
    float e = __expf(2.0f * x);
    return 1.0f - 2.0f / (e + 1.0f);
}
__device__ __forceinline__ unsigned short bf16_rtn(float x) {
    unsigned int u = __float_as_uint(x);
    unsigned int r = u + 0x7FFFu + ((u >> 16) & 1u);
    return (unsigned short)(r >> 16);
}
__device__ __forceinline__ float bf16_f32(unsigned short h) {
    return __uint_as_float(((unsigned int)h) << 16);
}

// ---------------- Prep: Kt_hi/Kt_lo[NP][FF] bf16 (transposed, hi/lo split) -------
__global__ void prep_kt_kernel(const float* __restrict__ K,
                               unsigned short* __restrict__ kt_hi,
                               unsigned short* __restrict__ kt_lo) {
    const int c = threadIdx.x;
    if (c >= NP) return;
    for (int k = 0; k < FF; ++k) {
        float v = (c < ZN) ? K[k * ZN + c] : 0.0f;
        unsigned short h = bf16_rtn(v);
        float lo = v - bf16_f32(h);
        kt_hi[c * FF + k] = h;
        kt_lo[c * FF + k] = bf16_rtn(lo);
    }
}

// ---------------- Kernel A: zx = x @ K + bias via bf16x2-split MFMA --------------
// Round-3 core (verified absmax 1.9e-6) + NEW coalesced epilogue: accs -> LDS
// (stride 212) -> flat copy where lane stores are exactly linear (4*f) ->
// full-width coalesced zx writes instead of 64B MFMA-layout segments.
__launch_bounds__(256, 2)
__global__ void xk_mfma_kernel(const float* __restrict__ x,
                               const unsigned short* __restrict__ kt_hi,
                               const unsigned short* __restrict__ kt_lo,
                               const float* __restrict__ bias,
                               float* __restrict__ zx) {
    __shared__ __align__(16) char xlds[2 * BM * FF * 2];   // 64 KiB; reused by epilogue

    const int tid = threadIdx.x;
    const size_t rowbase = (size_t)blockIdx.x * BM;
    const float* xb = x + rowbase * FF;

    const float4* gx = (const float4*)xb;
    #pragma unroll
    for (int i = 0; i < 16; ++i) {
        float4 v = gx[tid + 256 * i];
        const int fidx = (tid + 256 * i) * 4;
        const int row = fidx >> 7;
        const int col = fidx & 127;
        unsigned short h0 = bf16_rtn(v.x), h1 = bf16_rtn(v.y),
                       h2 = bf16_rtn(v.z), h3 = bf16_rtn(v.w);
        bhalf4 hv = { (short)h0, (short)h1, (short)h2, (short)h3 };
        bhalf4 lv = { (short)bf16_rtn(v.x - bf16_f32(h0)),
                      (short)bf16_rtn(v.y - bf16_f32(h1)),
                      (short)bf16_rtn(v.z - bf16_f32(h2)),
                      (short)bf16_rtn(v.w - bf16_f32(h3)) };
        const unsigned byte = (unsigned)((row << 8) + (col << 1)) ^ (((unsigned)row & 7u) << 4);
        *(bhalf4*)(xlds + byte)         = hv;
        *(bhalf4*)(xlds + 32768 + byte) = lv;
    }
    __syncthreads();

    const int w = tid >> 6, l = tid & 63;
    const int lrow = l & 15;
    const int lk   = (l >> 4) << 3;

    float bv[NT];
    #pragma unroll
    for (int nt = 0; nt < NT; ++nt) {
        const int cidx = nt * 16 + lrow;
        bv[nt] = (cidx < ZN) ? bias[cidx] : 0.0f;
    }

    f32x4 acc0[NT], acc1[NT];
    #pragma unroll
    for (int nt = 0; nt < NT; ++nt) { acc0[nt] = (f32x4)0.0f; acc1[nt] = (f32x4)0.0f; }

    #pragma unroll
    for (int ks = 0; ks < 4; ++ks) {
        const int kbyte = (ks * 32 + lk) * 2;
        const int row0 = (w << 5) + lrow;
        const int row1 = row0 + 16;
        const unsigned b0 = (unsigned)((row0 << 8) + kbyte) ^ (((unsigned)row0 & 7u) << 4);
        const unsigned b1 = (unsigned)((row1 << 8) + kbyte) ^ (((unsigned)row1 & 7u) << 4);
        bhalf8 aH0 = *(const bhalf8*)(xlds + b0);
        bhalf8 aL0 = *(const bhalf8*)(xlds + 32768 + b0);
        bhalf8 aH1 = *(const bhalf8*)(xlds + b1);
        bhalf8 aL1 = *(const bhalf8*)(xlds + 32768 + b1);
        #pragma unroll
        for (int nt = 0; nt < NT; ++nt) {
            const int col = nt * 16 + lrow;
            const size_t koff = ((size_t)col << 7) + (size_t)(ks * 32 + lk);
            bhalf8 bH = *(const bhalf8*)(kt_hi + koff);
            bhalf8 bL = *(const bhalf8*)(kt_lo + koff);
            acc0[nt] = __builtin_amdgcn_mfma_f32_16x16x32_bf16(aH0, bH, acc0[nt], 0, 0, 0);
            acc0[nt] = __builtin_amdgcn_mfma_f32_16x16x32_bf16(aH0, bL, acc0[nt], 0, 0, 0);
            acc0[nt] = __builtin_amdgcn_mfma_f32_16x16x32_bf16(aL0, bH, acc0[nt], 0, 0, 0);
            acc1[nt] = __builtin_amdgcn_mfma_f32_16x16x32_bf16(aH1, bH, acc1[nt], 0, 0, 0);
            acc1[nt] = __builtin_amdgcn_mfma_f32_16x16x32_bf16(aH1, bL, acc1[nt], 0, 0, 0);
            acc1[nt] = __builtin_amdgcn_mfma_f32_16x16x32_bf16(aL1, bH, acc1[nt], 0, 0, 0);
        }
    }

    // ---- NEW epilogue: two half-dumps (rows 0-63, 64-127) via LDS, coalesced ----
    float* elds = (float*)xlds;                 // [64][ESTRIDE] fp32 = 54.3 KB
    const int rsub = (l >> 4) << 2;
    #pragma unroll
    for (int half = 0; half < 2; ++half) {
        __syncthreads();                        // protect xlds reuse / prev copy
        if ((w >> 1) == half) {
            const int lr = (w & 1) * 32;        // local row base within half
            #pragma unroll
            for (int nt = 0; nt < NT; ++nt) {
                #pragma unroll
                for (int r = 0; r < 4; ++r) {
                    elds[(lr + rsub + r) * ESTRIDE + nt * 16 + lrow]      = acc0[nt][r] + bv[nt];
                    elds[(lr + 16 + rsub + r) * ESTRIDE + nt * 16 + lrow] = acc1[nt][r] + bv[nt];
                }
            }
        }
        __syncthreads();
        // flat copy: f -> (row=f/50, c4=f%50); zx addr = 4*f (exactly linear)
        for (int f = tid; f < 64 * 50; f += 256) {
            const int row = f / 50;
            const int c4 = f - row * 50;
            float4 v = *(const float4*)&elds[row * ESTRIDE + c4 * 4];
            *(float4*)&zx[(rowbase + half * 64 + row) * ZN + c4 * 4] = v;
        }
    }
}

// ---------------- Kernel B: scan, group-8 prefetch, 1 barrier/step ---------------
// Key fix: __syncthreads drains vmcnt(0) -> per-step HBM prefetch loads were
// paying full ~900cyc latency EVERY step (r2/r3/r5). Now all 16 loads for the
// next 8-step group are issued together at group start; only the group's first
// barrier drains them. Gates replicated per-wave (own hs copy + cA/cB regs),
// zs double-buffered by parity -> single barrier per step.
#define GATES(PP) do {                                                        \
    if (l < UU) {                                                             \
        float zi = zs[PP][0][l];                                              \
        float zf = zs[PP][0][l + UU];                                         \
        float zg = zs[PP][0][l + 2 * UU];                                     \
        float zo = zs[PP][0][l + 3 * UU];                                     \
        float gi = sigmoid_fast(zi), gf = sigmoid_fast(zf);                   \
        float go = sigmoid_fast(zo), gg = tanh_fast(zg);                      \
        cA = gf * cA + gi * gg;                                               \
        hs[w][0][l] = go * tanh_fast(cA);                                     \
        zi = zs[PP][1][l];                                                    \
        zf = zs[PP][1][l + UU];                                               \
        zg = zs[PP][1][l + 2 * UU];                                           \
        zo = zs[PP][1][l + 3 * UU];                                           \
        gi = sigmoid_fast(zi); gf = sigmoid_fast(zf);                         \
        go = sigmoid_fast(zo); gg = tanh_fast(zg);                            \
        cB = gf * cB + gi * gg;                                               \
        hs[w][1][l] = go * tanh_fast(cB);                                     \
    }                                                                         \
} while (0)

#define ZCOMP(P, VA, VB) do {                                                 \
    if (j < ZN) {                                                             \
        float a0 = (VA), a1 = 0.f, b0 = (VB), b1 = 0.f;                       \
        const float4* rp = (const float4*)&Rt[(size_t)j * RSTRIDE];           \
        const float4* h0 = (const float4*)hs[w][0];                           \
        const float4* h1 = (const float4*)hs[w][1];                           \
        _Pragma("unroll")                                                     \
        for (int k4 = 0; k4 < 13; ++k4) {                                     \
            float4 rv = rp[k4];                                               \
            float4 hv0 = h0[k4];                                              \
            float4 hv1 = h1[k4];                                              \
            a0 = fmaf(rv.x, hv0.x, a0); a1 = fmaf(rv.y, hv0.y, a1);           \
            a0 = fmaf(rv.z, hv0.z, a0); a1 = fmaf(rv.w, hv0.w, a1);           \
            b0 = fmaf(rv.x, hv1.x, b0); b1 = fmaf(rv.y, hv1.y, b1);           \
            b0 = fmaf(rv.z, hv1.z, b0); b1 = fmaf(rv.w, hv1.w, b1);           \
        }                                                                     \
        zs[P][0][j] = a0 + a1;                                                \
        zs[P][1][j] = b0 + b1;                                                \
    }                                                                         \
} while (0)

// Group of 8 steps t = T0..T0+7 (T0 % 8 == 0). Consumes CA/CB, preloads NA/NB
// for the next group (clamped; final group's loads are dead and DCE'd).
#define GROUP8(CA, CB, NA, NB, T0, FIRST) do {                                \
    _Pragma("unroll")                                                         \
    for (int s = 0; s < 8; ++s) {                                             \
        int tn = (T0) + 8 + s; if (tn > TT - 1) tn = TT - 1;                  \
        NA[s] = (j < ZN) ? zpA[(size_t)tn * ZN + j] : 0.0f;                   \
        NB[s] = (j < ZN) ? zpB[(size_t)tn * ZN + j] : 0.0f;                   \
    }                                                                         \
    if (!(FIRST)) GATES(1);                                                   \
    ZCOMP(0, CA[0], CB[0]); __syncthreads();                                  \
    GATES(0); ZCOMP(1, CA[1], CB[1]); __syncthreads();                        \
    GATES(1); ZCOMP(0, CA[2], CB[2]); __syncthreads();                        \
    GATES(0); ZCOMP(1, CA[3], CB[3]); __syncthreads();                        \
    GATES(1); ZCOMP(0, CA[4], CB[4]); __syncthreads();                        \
    GATES(0); ZCOMP(1, CA[5], CB[5]); __syncthreads();                        \
    GATES(1); ZCOMP(0, CA[6], CB[6]); __syncthreads();                        \
    GATES(0); ZCOMP(1, CA[7], CB[7]); __syncthreads();                        \
} while (0)

__launch_bounds__(256, 1)
__global__ void lstm_scan3_kernel(const float* __restrict__ zx,
                                  const float* __restrict__ R,
                                  const float* __restrict__ dw,
                                  const float* __restrict__ db,
                                  float* __restrict__ out) {
    const int tid = threadIdx.x;
    const int w = tid >> 6;
    const int l = tid & 63;
    const int j = tid;

    __shared__ __align__(16) float Rt[ZN * RSTRIDE];   // 41600 B
    __shared__ __align__(16) float zs[2][2][ZN];       // [parity][batch] 3200 B
    __shared__ __align__(16) float hs[4][2][56];       // [wave][batch][unit] 1792 B

    for (int idx = tid; idx < UU * ZN; idx += 256) {
        const int k = idx / ZN;
        const int ccol = idx - k * ZN;
        Rt[(size_t)ccol * RSTRIDE + k] = R[idx];
    }
    if (tid < ZN) { Rt[(size_t)tid * RSTRIDE + 50] = 0.0f; Rt[(size_t)tid * RSTRIDE + 51] = 0.0f; }
    for (int idx = tid; idx < 4 * 2 * 56; idx += 256) ((float*)hs)[idx] = 0.0f;

    const float* zpA = zx + (size_t)(2 * blockIdx.x + 0) * TT * ZN;
    const float* zpB = zx + (size_t)(2 * blockIdx.x + 1) * TT * ZN;

    float cA = 0.0f, cB = 0.0f;

    float pA[8], pB[8], qA[8], qB[8];
    #pragma unroll
    for (int s = 0; s < 8; ++s) {
        pA[s] = (j < ZN) ? zpA[(size_t)s * ZN + j] : 0.0f;
        pB[s] = (j < ZN) ? zpB[(size_t)s * ZN + j] : 0.0f;
    }
    __syncthreads();

    GROUP8(pA, pB, qA, qB, 0, true);                       // t = 0..7
    for (int gg = 0; gg < 63; ++gg) {                      // t = 8..1015
        GROUP8(qA, qB, pA, pB, 8 + gg * 16, false);
        GROUP8(pA, pB, qA, qB, 16 + gg * 16, false);
    }
    GROUP8(qA, qB, pA, pB, 1016, false);                   // t = 1016..1023

    GATES(1);                                              // step 1023's gates
    __syncthreads();
    if (tid < 2) {
        float s = db[0];
        const float* hrow = hs[0][tid];
        #pragma unroll
        for (int u = 0; u < UU; ++u) s = fmaf(hrow[u], dw[u], s);
        out[2 * blockIdx.x + tid] = s;
    }
}

// ---------------- Fallback GEMM (round-2, slow but correct) ----------------------
__launch_bounds__(256, 1)
__global__ void xk_gemm_kernel(const float* __restrict__ x,
                               const float* __restrict__ K,
                               const float* __restrict__ bias,
                               float* __restrict__ zx) {
    const int b = blockIdx.x;
    const int j = threadIdx.x;

    __shared__ __align__(16) float xs[2][RPP * FF];

    float kreg[FF];
    float bj = 0.0f;
    if (j < ZN) {
        #pragma unroll
        for (int k = 0; k < FF; ++k) kreg[k] = K[k * ZN + j];
        bj = bias[j];
    }

    const float* xrow = x + (size_t)b * TT * FF;
    float* zrow = zx + (size_t)b * TT * ZN;

    ((float4*)xs[0])[threadIdx.x] = ((const float4*)xrow)[threadIdx.x];
    __syncthreads();

    const int NPASS = TT / RPP;
    for (int p = 0; p < NPASS; ++p) {
        const int cur = p & 1, nxt = cur ^ 1;
        float4 gxv;
        const bool more = (p + 1) < NPASS;
        if (more) gxv = ((const float4*)(xrow + (size_t)(p + 1) * RPP * FF))[threadIdx.x];

        if (j < ZN) {
            float acc[RPP];
            #pragma unroll
            for (int r = 0; r < RPP; ++r) acc[r] = bj;
            const float4* xb4 = (const float4*)xs[cur];
            #pragma unroll
            for (int k4 = 0; k4 < FF / 4; ++k4) {
                #pragma unroll
                for (int r = 0; r < RPP; ++r) {
                    float4 xv = xb4[r * (FF / 4) + k4];
                    acc[r] = fmaf(xv.x, kreg[4 * k4 + 0], acc[r]);
                    acc[r] = fmaf(xv.y, kreg[4 * k4 + 1], acc[r]);
                    acc[r] = fmaf(xv.z, kreg[4 * k4 + 2], acc[r]);
                    acc[r] = fmaf(xv.w, kreg[4 * k4 + 3], acc[r]);
                }
            }
            float* zpo = zrow + (size_t)p * RPP * ZN + j;
            #pragma unroll
            for (int r = 0; r < RPP; ++r) zpo[r * ZN] = acc[r];
        }
        if (more) ((float4*)xs[nxt])[threadIdx.x] = gxv;
        __syncthreads();
    }
}

extern "C" void kernel_launch(void* const* d_in, const int* in_sizes, int n_in,
                              void* d_out, int out_size, void* d_ws, size_t ws_size,
                              hipStream_t stream) {
    const float* x    = (const float*)d_in[0];  // [512,1024,128]
    const float* K    = (const float*)d_in[1];  // [128,200]
    const float* R    = (const float*)d_in[2];  // [50,200]
    const float* bias = (const float*)d_in[3];  // [200]
    const float* dw   = (const float*)d_in[4];  // [50,1]
    const float* db   = (const float*)d_in[5];  // [1]
    float* out = (float*)d_out;                 // [512,1]

    const size_t zx_bytes = (size_t)MROWS * ZN * sizeof(float);          // 419.43 MB
    const size_t kt_elems = (size_t)NP * FF;
    const size_t kt_bytes = kt_elems * sizeof(unsigned short);

    if (ws_size >= zx_bytes + 2 * kt_bytes) {
        float* zx = (float*)d_ws;
        unsigned short* kt_hi = (unsigned short*)((char*)d_ws + zx_bytes);
        unsigned short* kt_lo = kt_hi + kt_elems;
        prep_kt_kernel<<<1, 256, 0, stream>>>(K, kt_hi, kt_lo);
        xk_mfma_kernel<<<MROWS / BM, 256, 0, stream>>>(x, kt_hi, kt_lo, bias, zx);
        lstm_scan3_kernel<<<BATCH / 2, 256, 0, stream>>>(zx, R, dw, db, out);
    } else if (ws_size >= zx_bytes) {
        float* zx = (float*)d_ws;
        xk_gemm_kernel<<<BATCH, 256, 0, stream>>>(x, K, bias, zx);
        lstm_scan3_kernel<<<BATCH / 2, 256, 0, stream>>>(zx, R, dw, db, out);
    }
}

// Round 7
// 1099.263 us; speedup vs baseline: 1.2099x; 1.2099x over previous
//
#include <hip/hip_runtime.h>
#include <math.h>

#define BATCH 512
#define TT    1024
#define FF    128
#define UU    50
#define ZN    200          // 4*UU
#define NP    208          // padded N (13 * 16)
#define NT    13           // N tiles of 16
#define MROWS (BATCH * TT) // 524288
#define BM    128          // rows per GEMM block
#define RPP   8            // rows per pass in fallback GEMM
#define ESTRIDE 212        // GEMM epilogue LDS row stride

typedef __attribute__((ext_vector_type(8))) short bhalf8;
typedef __attribute__((ext_vector_type(4))) short bhalf4;
typedef __attribute__((ext_vector_type(4))) float f32x4;

__device__ __forceinline__ float sigmoid_fast(float x) {
    return 1.0f / (1.0f + __expf(-x));
}
__device__ __forceinline__ float tanh_fast(float x) {
    float e = __expf(2.0f * x);
    return 1.0f - 2.0f / (e + 1.0f);
}
__device__ __forceinline__ unsigned short bf16_rtn(float x) {
    unsigned int u = __float_as_uint(x);
    unsigned int r = u + 0x7FFFu + ((u >> 16) & 1u);
    return (unsigned short)(r >> 16);
}
__device__ __forceinline__ float bf16_f32(unsigned short h) {
    return __uint_as_float(((unsigned int)h) << 16);
}
// wave-uniform broadcast of lane u's value (VALU; avoids the shared LDS pipe)
__device__ __forceinline__ float rdlane(float v, int u) {
    return __int_as_float(__builtin_amdgcn_readlane(__float_as_int(v), u));
}

// ---------------- Prep: Kt_hi/Kt_lo[NP][FF] bf16 (transposed, hi/lo split) -------
__global__ void prep_kt_kernel(const float* __restrict__ K,
                               unsigned short* __restrict__ kt_hi,
                               unsigned short* __restrict__ kt_lo) {
    const int c = threadIdx.x;
    if (c >= NP) return;
    for (int k = 0; k < FF; ++k) {
        float v = (c < ZN) ? K[k * ZN + c] : 0.0f;
        unsigned short h = bf16_rtn(v);
        float lo = v - bf16_f32(h);
        kt_hi[c * FF + k] = h;
        kt_lo[c * FF + k] = bf16_rtn(lo);
    }
}

// ---------------- Kernel A: zx = x @ K + bias via bf16x2-split MFMA --------------
// (unchanged from round 6 — verified)
__launch_bounds__(256, 2)
__global__ void xk_mfma_kernel(const float* __restrict__ x,
                               const unsigned short* __restrict__ kt_hi,
                               const unsigned short* __restrict__ kt_lo,
                               const float* __restrict__ bias,
                               float* __restrict__ zx) {
    __shared__ __align__(16) char xlds[2 * BM * FF * 2];   // 64 KiB; reused by epilogue

    const int tid = threadIdx.x;
    const size_t rowbase = (size_t)blockIdx.x * BM;
    const float* xb = x + rowbase * FF;

    const float4* gx = (const float4*)xb;
    #pragma unroll
    for (int i = 0; i < 16; ++i) {
        float4 v = gx[tid + 256 * i];
        const int fidx = (tid + 256 * i) * 4;
        const int row = fidx >> 7;
        const int col = fidx & 127;
        unsigned short h0 = bf16_rtn(v.x), h1 = bf16_rtn(v.y),
                       h2 = bf16_rtn(v.z), h3 = bf16_rtn(v.w);
        bhalf4 hv = { (short)h0, (short)h1, (short)h2, (short)h3 };
        bhalf4 lv = { (short)bf16_rtn(v.x - bf16_f32(h0)),
                      (short)bf16_rtn(v.y - bf16_f32(h1)),
                      (short)bf16_rtn(v.z - bf16_f32(h2)),
                      (short)bf16_rtn(v.w - bf16_f32(h3)) };
        const unsigned byte = (unsigned)((row << 8) + (col << 1)) ^ (((unsigned)row & 7u) << 4);
        *(bhalf4*)(xlds + byte)         = hv;
        *(bhalf4*)(xlds + 32768 + byte) = lv;
    }
    __syncthreads();

    const int w = tid >> 6, l = tid & 63;
    const int lrow = l & 15;
    const int lk   = (l >> 4) << 3;

    float bv[NT];
    #pragma unroll
    for (int nt = 0; nt < NT; ++nt) {
        const int cidx = nt * 16 + lrow;
        bv[nt] = (cidx < ZN) ? bias[cidx] : 0.0f;
    }

    f32x4 acc0[NT], acc1[NT];
    #pragma unroll
    for (int nt = 0; nt < NT; ++nt) { acc0[nt] = (f32x4)0.0f; acc1[nt] = (f32x4)0.0f; }

    #pragma unroll
    for (int ks = 0; ks < 4; ++ks) {
        const int kbyte = (ks * 32 + lk) * 2;
        const int row0 = (w << 5) + lrow;
        const int row1 = row0 + 16;
        const unsigned b0 = (unsigned)((row0 << 8) + kbyte) ^ (((unsigned)row0 & 7u) << 4);
        const unsigned b1 = (unsigned)((row1 << 8) + kbyte) ^ (((unsigned)row1 & 7u) << 4);
        bhalf8 aH0 = *(const bhalf8*)(xlds + b0);
        bhalf8 aL0 = *(const bhalf8*)(xlds + 32768 + b0);
        bhalf8 aH1 = *(const bhalf8*)(xlds + b1);
        bhalf8 aL1 = *(const bhalf8*)(xlds + 32768 + b1);
        #pragma unroll
        for (int nt = 0; nt < NT; ++nt) {
            const int col = nt * 16 + lrow;
            const size_t koff = ((size_t)col << 7) + (size_t)(ks * 32 + lk);
            bhalf8 bH = *(const bhalf8*)(kt_hi + koff);
            bhalf8 bL = *(const bhalf8*)(kt_lo + koff);
            acc0[nt] = __builtin_amdgcn_mfma_f32_16x16x32_bf16(aH0, bH, acc0[nt], 0, 0, 0);
            acc0[nt] = __builtin_amdgcn_mfma_f32_16x16x32_bf16(aH0, bL, acc0[nt], 0, 0, 0);
            acc0[nt] = __builtin_amdgcn_mfma_f32_16x16x32_bf16(aL0, bH, acc0[nt], 0, 0, 0);
            acc1[nt] = __builtin_amdgcn_mfma_f32_16x16x32_bf16(aH1, bH, acc1[nt], 0, 0, 0);
            acc1[nt] = __builtin_amdgcn_mfma_f32_16x16x32_bf16(aH1, bL, acc1[nt], 0, 0, 0);
            acc1[nt] = __builtin_amdgcn_mfma_f32_16x16x32_bf16(aL1, bH, acc1[nt], 0, 0, 0);
        }
    }

    float* elds = (float*)xlds;
    const int rsub = (l >> 4) << 2;
    #pragma unroll
    for (int half = 0; half < 2; ++half) {
        __syncthreads();
        if ((w >> 1) == half) {
            const int lr = (w & 1) * 32;
            #pragma unroll
            for (int nt = 0; nt < NT; ++nt) {
                #pragma unroll
                for (int r = 0; r < 4; ++r) {
                    elds[(lr + rsub + r) * ESTRIDE + nt * 16 + lrow]      = acc0[nt][r] + bv[nt];
                    elds[(lr + 16 + rsub + r) * ESTRIDE + nt * 16 + lrow] = acc1[nt][r] + bv[nt];
                }
            }
        }
        __syncthreads();
        for (int f = tid; f < 64 * 50; f += 256) {
            const int row = f / 50;
            const int c4 = f - row * 50;
            float4 v = *(const float4*)&elds[row * ESTRIDE + c4 * 4];
            *(float4*)&zx[(rowbase + half * 64 + row) * ZN + c4 * 4] = v;
        }
    }
}

// ---------------- Kernel B: scan7 — R in pinned VGPRs, readlane h-broadcast ------
// 1 batch/block, grid 512 (2 blocks/CU -> cross-block stall hiding). Thread tid<200
// owns column tid with R[:,col] in 50 asm-pinned VGPRs. Gates replicated per wave
// (lanes<50, identical), h/c in lane regs; h broadcast via readlane (VALU pipe).
// Inner-loop LDS = 1 write + 4 reads per thread per step; ONE barrier per step.
#define STEP(ZXV, P) do {                                                     \
    float a0 = (ZXV), a1 = 0.f, a2 = 0.f, a3 = 0.f;                           \
    _Pragma("unroll")                                                         \
    for (int u = 0; u < 48; u += 4) {                                         \
        float h0 = rdlane(h, u), h1 = rdlane(h, u + 1);                       \
        float h2 = rdlane(h, u + 2), h3 = rdlane(h, u + 3);                   \
        a0 = fmaf(h0, r[u], a0);     a1 = fmaf(h1, r[u + 1], a1);             \
        a2 = fmaf(h2, r[u + 2], a2); a3 = fmaf(h3, r[u + 3], a3);             \
    }                                                                         \
    a0 = fmaf(rdlane(h, 48), r[48], a0);                                      \
    a1 = fmaf(rdlane(h, 49), r[49], a1);                                      \
    if (col < ZN) zs[P][col] = (a0 + a1) + (a2 + a3);                         \
    __syncthreads();                                                          \
    if (l < UU) {                                                             \
        float zi = zs[P][l];                                                  \
        float zf = zs[P][l + UU];                                             \
        float zg = zs[P][l + 2 * UU];                                         \
        float zo = zs[P][l + 3 * UU];                                         \
        float gi = sigmoid_fast(zi), gf = sigmoid_fast(zf);                   \
        float go = sigmoid_fast(zo), gg = tanh_fast(zg);                      \
        c = gf * c + gi * gg;                                                 \
        h = go * tanh_fast(c);                                                \
    }                                                                         \
} while (0)

#define ISSUE8(DST, T0) do {                                                  \
    _Pragma("unroll")                                                         \
    for (int s = 0; s < 8; ++s) {                                             \
        int tt = (T0) + s; if (tt > TT - 1) tt = TT - 1;                      \
        DST[s] = (col < ZN) ? zp[(size_t)tt * ZN + col] : 0.0f;               \
    }                                                                         \
} while (0)

#define STEPS8(SRC) do {                                                      \
    STEP(SRC[0], 0); STEP(SRC[1], 1); STEP(SRC[2], 0); STEP(SRC[3], 1);       \
    STEP(SRC[4], 0); STEP(SRC[5], 1); STEP(SRC[6], 0); STEP(SRC[7], 1);       \
} while (0)

__launch_bounds__(256, 2)
__global__ void lstm_scan7_kernel(const float* __restrict__ zx,
                                  const float* __restrict__ R,
                                  const float* __restrict__ dw,
                                  const float* __restrict__ db,
                                  float* __restrict__ out) {
    const int tid = threadIdx.x;
    const int l = tid & 63;
    const int col = tid;                 // column ownership (col<200 active)

    __shared__ __align__(16) float zs[2][ZN];   // parity-buffered pre-activations

    // R column in named, asm-pinned VGPRs (defeats compiler remat-from-global)
    float r[UU];
    #pragma unroll
    for (int u = 0; u < UU; ++u) r[u] = (col < ZN) ? R[u * ZN + col] : 0.0f;
    #pragma unroll
    for (int u = 0; u < UU; ++u) asm volatile("" : "+v"(r[u]));

    const float dwv = (l < UU) ? dw[l] : 0.0f;

    float h = 0.0f, c = 0.0f;            // unit state in lanes l<50 (per-wave copy)
    const float* zp = zx + (size_t)blockIdx.x * TT * ZN;

    float pf[8], qf[8];
    ISSUE8(pf, 0);
    __syncthreads();

    for (int t = 0; t < TT; t += 16) {
        ISSUE8(qf, t + 8);               // loads drain at first barrier in STEPS8
        STEPS8(pf);                      // steps t .. t+7
        ISSUE8(pf, t + 16);              // clamped (dead) on the final iteration
        STEPS8(qf);                      // steps t+8 .. t+15
    }

    // epilogue: out[b] = h . dense_w + dense_b  (wave 0; shuffle reduction)
    if ((tid >> 6) == 0) {
        float s = (l < UU) ? h * dwv : 0.0f;
        #pragma unroll
        for (int off = 32; off > 0; off >>= 1) s += __shfl_down(s, off, 64);
        if (l == 0) out[blockIdx.x] = s + db[0];
    }
}

// ---------------- Fallback GEMM (round-2, slow but correct) ----------------------
__launch_bounds__(256, 1)
__global__ void xk_gemm_kernel(const float* __restrict__ x,
                               const float* __restrict__ K,
                               const float* __restrict__ bias,
                               float* __restrict__ zx) {
    const int b = blockIdx.x;
    const int j = threadIdx.x;

    __shared__ __align__(16) float xs[2][RPP * FF];

    float kreg[FF];
    float bj = 0.0f;
    if (j < ZN) {
        #pragma unroll
        for (int k = 0; k < FF; ++k) kreg[k] = K[k * ZN + j];
        bj = bias[j];
    }

    const float* xrow = x + (size_t)b * TT * FF;
    float* zrow = zx + (size_t)b * TT * ZN;

    ((float4*)xs[0])[threadIdx.x] = ((const float4*)xrow)[threadIdx.x];
    __syncthreads();

    const int NPASS = TT / RPP;
    for (int p = 0; p < NPASS; ++p) {
        const int cur = p & 1, nxt = cur ^ 1;
        float4 gxv;
        const bool more = (p + 1) < NPASS;
        if (more) gxv = ((const float4*)(xrow + (size_t)(p + 1) * RPP * FF))[threadIdx.x];

        if (j < ZN) {
            float acc[RPP];
            #pragma unroll
            for (int r = 0; r < RPP; ++r) acc[r] = bj;
            const float4* xb4 = (const float4*)xs[cur];
            #pragma unroll
            for (int k4 = 0; k4 < FF / 4; ++k4) {
                #pragma unroll
                for (int r = 0; r < RPP; ++r) {
                    float4 xv = xb4[r * (FF / 4) + k4];
                    acc[r] = fmaf(xv.x, kreg[4 * k4 + 0], acc[r]);
                    acc[r] = fmaf(xv.y, kreg[4 * k4 + 1], acc[r]);
                    acc[r] = fmaf(xv.z, kreg[4 * k4 + 2], acc[r]);
                    acc[r] = fmaf(xv.w, kreg[4 * k4 + 3], acc[r]);
                }
            }
            float* zpo = zrow + (size_t)p * RPP * ZN + j;
            #pragma unroll
            for (int r = 0; r < RPP; ++r) zpo[r * ZN] = acc[r];
        }
        if (more) ((float4*)xs[nxt])[threadIdx.x] = gxv;
        __syncthreads();
    }
}

extern "C" void kernel_launch(void* const* d_in, const int* in_sizes, int n_in,
                              void* d_out, int out_size, void* d_ws, size_t ws_size,
                              hipStream_t stream) {
    const float* x    = (const float*)d_in[0];  // [512,1024,128]
    const float* K    = (const float*)d_in[1];  // [128,200]
    const float* R    = (const float*)d_in[2];  // [50,200]
    const float* bias = (const float*)d_in[3];  // [200]
    const float* dw   = (const float*)d_in[4];  // [50,1]
    const float* db   = (const float*)d_in[5];  // [1]
    float* out = (float*)d_out;                 // [512,1]

    const size_t zx_bytes = (size_t)MROWS * ZN * sizeof(float);          // 419.43 MB
    const size_t kt_elems = (size_t)NP * FF;
    const size_t kt_bytes = kt_elems * sizeof(unsigned short);

    if (ws_size >= zx_bytes + 2 * kt_bytes) {
        float* zx = (float*)d_ws;
        unsigned short* kt_hi = (unsigned short*)((char*)d_ws + zx_bytes);
        unsigned short* kt_lo = kt_hi + kt_elems;
        prep_kt_kernel<<<1, 256, 0, stream>>>(K, kt_hi, kt_lo);
        xk_mfma_kernel<<<MROWS / BM, 256, 0, stream>>>(x, kt_hi, kt_lo, bias, zx);
        lstm_scan7_kernel<<<BATCH, 256, 0, stream>>>(zx, R, dw, db, out);
    } else if (ws_size >= zx_bytes) {
        float* zx = (float*)d_ws;
        xk_gemm_kernel<<<BATCH, 256, 0, stream>>>(x, K, bias, zx);
        lstm_scan7_kernel<<<BATCH, 256, 0, stream>>>(zx, R, dw, db, out);
    }
}

// Round 8
// 996.084 us; speedup vs baseline: 1.3352x; 1.1036x over previous
//
#include <hip/hip_runtime.h>
#include <math.h>

#define BATCH 512
#define TT    1024
#define FF    128
#define UU    50
#define ZN    200          // 4*UU
#define NP    208          // padded N (13 * 16)
#define NT    13           // N tiles of 16
#define MROWS (BATCH * TT) // 524288
#define BM    128          // rows per GEMM block
#define RPP   8            // rows per pass in fallback GEMM
#define ESTRIDE 212        // GEMM epilogue LDS row stride

typedef __attribute__((ext_vector_type(8))) short bhalf8;
typedef __attribute__((ext_vector_type(4))) short bhalf4;
typedef __attribute__((ext_vector_type(4))) float f32x4;

__device__ __forceinline__ float rcp_fast(float x) {
    return __builtin_amdgcn_rcpf(x);          // v_rcp_f32 (~1ulp; fine vs 6.7e-3 thr)
}
__device__ __forceinline__ float sigmoid_fast(float x) {
    // 1/(1+2^(-x*log2e)) : mul + v_exp + add + v_rcp = 4 insts (no div sequence)
    return rcp_fast(1.0f + __builtin_amdgcn_exp2f(-1.442695041f * x));
}
__device__ __forceinline__ float tanh_fast(float x) {
    float e = __builtin_amdgcn_exp2f(2.885390082f * x);   // 2^(2x*log2e)
    return fmaf(-2.0f, rcp_fast(e + 1.0f), 1.0f);
}
__device__ __forceinline__ unsigned short bf16_rtn(float x) {
    unsigned int u = __float_as_uint(x);
    unsigned int r = u + 0x7FFFu + ((u >> 16) & 1u);
    return (unsigned short)(r >> 16);
}
__device__ __forceinline__ float bf16_f32(unsigned short h) {
    return __uint_as_float(((unsigned int)h) << 16);
}
// wave-uniform broadcast of lane u's value (VALU pipe; exec-independent)
__device__ __forceinline__ float rdlane(float v, int u) {
    return __int_as_float(__builtin_amdgcn_readlane(__float_as_int(v), u));
}

// ---------------- Prep: Kt_hi/Kt_lo[NP][FF] bf16 (transposed, hi/lo split) -------
__global__ void prep_kt_kernel(const float* __restrict__ K,
                               unsigned short* __restrict__ kt_hi,
                               unsigned short* __restrict__ kt_lo) {
    const int c = threadIdx.x;
    if (c >= NP) return;
    for (int k = 0; k < FF; ++k) {
        float v = (c < ZN) ? K[k * ZN + c] : 0.0f;
        unsigned short h = bf16_rtn(v);
        float lo = v - bf16_f32(h);
        kt_hi[c * FF + k] = h;
        kt_lo[c * FF + k] = bf16_rtn(lo);
    }
}

// ---------------- Kernel A: zx = x @ K + bias via bf16x2-split MFMA --------------
// Round-3 core (verified). Epilogue now PERMUTES to the scan-friendly layout:
// zx4[m][u*4+g] = z[m][g*50+u]  (gate-tuple per unit, float4-readable by lane u).
__launch_bounds__(256, 2)
__global__ void xk_mfma_kernel(const float* __restrict__ x,
                               const unsigned short* __restrict__ kt_hi,
                               const unsigned short* __restrict__ kt_lo,
                               const float* __restrict__ bias,
                               float* __restrict__ zx) {
    __shared__ __align__(16) char xlds[2 * BM * FF * 2];   // 64 KiB; reused by epilogue

    const int tid = threadIdx.x;
    const size_t rowbase = (size_t)blockIdx.x * BM;
    const float* xb = x + rowbase * FF;

    const float4* gx = (const float4*)xb;
    #pragma unroll
    for (int i = 0; i < 16; ++i) {
        float4 v = gx[tid + 256 * i];
        const int fidx = (tid + 256 * i) * 4;
        const int row = fidx >> 7;
        const int col = fidx & 127;
        unsigned short h0 = bf16_rtn(v.x), h1 = bf16_rtn(v.y),
                       h2 = bf16_rtn(v.z), h3 = bf16_rtn(v.w);
        bhalf4 hv = { (short)h0, (short)h1, (short)h2, (short)h3 };
        bhalf4 lv = { (short)bf16_rtn(v.x - bf16_f32(h0)),
                      (short)bf16_rtn(v.y - bf16_f32(h1)),
                      (short)bf16_rtn(v.z - bf16_f32(h2)),
                      (short)bf16_rtn(v.w - bf16_f32(h3)) };
        const unsigned byte = (unsigned)((row << 8) + (col << 1)) ^ (((unsigned)row & 7u) << 4);
        *(bhalf4*)(xlds + byte)         = hv;
        *(bhalf4*)(xlds + 32768 + byte) = lv;
    }
    __syncthreads();

    const int w = tid >> 6, l = tid & 63;
    const int lrow = l & 15;
    const int lk   = (l >> 4) << 3;

    float bv[NT];
    #pragma unroll
    for (int nt = 0; nt < NT; ++nt) {
        const int cidx = nt * 16 + lrow;
        bv[nt] = (cidx < ZN) ? bias[cidx] : 0.0f;
    }

    f32x4 acc0[NT], acc1[NT];
    #pragma unroll
    for (int nt = 0; nt < NT; ++nt) { acc0[nt] = (f32x4)0.0f; acc1[nt] = (f32x4)0.0f; }

    #pragma unroll
    for (int ks = 0; ks < 4; ++ks) {
        const int kbyte = (ks * 32 + lk) * 2;
        const int row0 = (w << 5) + lrow;
        const int row1 = row0 + 16;
        const unsigned b0 = (unsigned)((row0 << 8) + kbyte) ^ (((unsigned)row0 & 7u) << 4);
        const unsigned b1 = (unsigned)((row1 << 8) + kbyte) ^ (((unsigned)row1 & 7u) << 4);
        bhalf8 aH0 = *(const bhalf8*)(xlds + b0);
        bhalf8 aL0 = *(const bhalf8*)(xlds + 32768 + b0);
        bhalf8 aH1 = *(const bhalf8*)(xlds + b1);
        bhalf8 aL1 = *(const bhalf8*)(xlds + 32768 + b1);
        #pragma unroll
        for (int nt = 0; nt < NT; ++nt) {
            const int col = nt * 16 + lrow;
            const size_t koff = ((size_t)col << 7) + (size_t)(ks * 32 + lk);
            bhalf8 bH = *(const bhalf8*)(kt_hi + koff);
            bhalf8 bL = *(const bhalf8*)(kt_lo + koff);
            acc0[nt] = __builtin_amdgcn_mfma_f32_16x16x32_bf16(aH0, bH, acc0[nt], 0, 0, 0);
            acc0[nt] = __builtin_amdgcn_mfma_f32_16x16x32_bf16(aH0, bL, acc0[nt], 0, 0, 0);
            acc0[nt] = __builtin_amdgcn_mfma_f32_16x16x32_bf16(aL0, bH, acc0[nt], 0, 0, 0);
            acc1[nt] = __builtin_amdgcn_mfma_f32_16x16x32_bf16(aH1, bH, acc1[nt], 0, 0, 0);
            acc1[nt] = __builtin_amdgcn_mfma_f32_16x16x32_bf16(aH1, bL, acc1[nt], 0, 0, 0);
            acc1[nt] = __builtin_amdgcn_mfma_f32_16x16x32_bf16(aL1, bH, acc1[nt], 0, 0, 0);
        }
    }

    float* elds = (float*)xlds;
    const int rsub = (l >> 4) << 2;
    #pragma unroll
    for (int half = 0; half < 2; ++half) {
        __syncthreads();
        if ((w >> 1) == half) {
            const int lr = (w & 1) * 32;
            #pragma unroll
            for (int nt = 0; nt < NT; ++nt) {
                #pragma unroll
                for (int r = 0; r < 4; ++r) {
                    elds[(lr + rsub + r) * ESTRIDE + nt * 16 + lrow]      = acc0[nt][r] + bv[nt];
                    elds[(lr + 16 + rsub + r) * ESTRIDE + nt * 16 + lrow] = acc1[nt][r] + bv[nt];
                }
            }
        }
        __syncthreads();
        // permuted copy: gather the 4 gate cols of unit u -> one coalesced float4
        for (int f = tid; f < 64 * 50; f += 256) {
            const int row = f / 50;
            const int u = f - row * 50;
            float4 v;
            v.x = elds[row * ESTRIDE + u];          // i  (col u)
            v.y = elds[row * ESTRIDE + u + 50];     // f
            v.z = elds[row * ESTRIDE + u + 100];    // g
            v.w = elds[row * ESTRIDE + u + 150];    // o
            *(float4*)&zx[(rowbase + half * 64 + row) * ZN + u * 4] = v;
        }
    }
}

// ---------------- Kernel B: scan8 — ONE WAVE PER BATCH, zero barriers/LDS --------
// Lane l<50 owns UNIT l: computes its own 4 gate pre-activations (cols l, l+50,
// l+100, l+150) -> gates are lane-local (no shuffle/LDS/barrier at all).
// R in 200 asm-pinned VGPRs (launch_bounds(64,1) -> 512-reg budget).
// h broadcast via intra-wave readlane: 50 rdl serve 200 FMAs per step.
// zx4 layout [m][u*4+g]: one coalesced float4 load per lane per step; group-8
// prefetch with NO barrier anywhere -> no vmcnt(0) drain ever.
#define ISSUE8(DST, T0) do {                                                  \
    _Pragma("unroll")                                                         \
    for (int s = 0; s < 8; ++s) {                                             \
        int tt = (T0) + s; if (tt > TT - 1) tt = TT - 1;                      \
        if (act) DST[s] = *(const float4*)&zp[(size_t)tt * ZN + l * 4];       \
    }                                                                         \
} while (0)

#define STEP8(V) do {                                                         \
    float a0 = (V).x, a1 = (V).y, a2 = (V).z, a3 = (V).w;                     \
    float e0 = 0.f, e1 = 0.f, e2 = 0.f, e3 = 0.f;                             \
    _Pragma("unroll")                                                         \
    for (int u = 0; u < UU; u += 2) {                                         \
        float h0 = rdlane(h, u), h1 = rdlane(h, u + 1);                       \
        a0 = fmaf(h0, r0[u], a0);  e0 = fmaf(h1, r0[u + 1], e0);              \
        a1 = fmaf(h0, r1[u], a1);  e1 = fmaf(h1, r1[u + 1], e1);              \
        a2 = fmaf(h0, r2[u], a2);  e2 = fmaf(h1, r2[u + 1], e2);              \
        a3 = fmaf(h0, r3[u], a3);  e3 = fmaf(h1, r3[u + 1], e3);              \
    }                                                                         \
    if (act) {                                                                \
        float zi = a0 + e0, zf = a1 + e1, zg = a2 + e2, zo = a3 + e3;         \
        float gi = sigmoid_fast(zi), gf = sigmoid_fast(zf);                   \
        float go = sigmoid_fast(zo), gg = tanh_fast(zg);                      \
        c = gf * c + gi * gg;                                                 \
        h = go * tanh_fast(c);                                                \
    }                                                                         \
} while (0)

#define STEPS8(SRC) do {                                                      \
    STEP8(SRC[0]); STEP8(SRC[1]); STEP8(SRC[2]); STEP8(SRC[3]);               \
    STEP8(SRC[4]); STEP8(SRC[5]); STEP8(SRC[6]); STEP8(SRC[7]);               \
} while (0)

__launch_bounds__(64, 1)
__global__ void lstm_scan8_kernel(const float* __restrict__ zx4,
                                  const float* __restrict__ R,
                                  const float* __restrict__ dw,
                                  const float* __restrict__ db,
                                  float* __restrict__ out) {
    const int l = threadIdx.x;           // lane 0..63
    const int b = blockIdx.x;            // batch
    const bool act = (l < UU);

    // R quadrant columns in registers: r{q}[u] = R[u][l + 50q]
    float r0[UU], r1[UU], r2[UU], r3[UU];
    #pragma unroll
    for (int u = 0; u < UU; ++u) {
        r0[u] = act ? R[u * ZN + l]       : 0.0f;
        r1[u] = act ? R[u * ZN + l + 50]  : 0.0f;
        r2[u] = act ? R[u * ZN + l + 100] : 0.0f;
        r3[u] = act ? R[u * ZN + l + 150] : 0.0f;
    }
    #pragma unroll
    for (int u = 0; u < UU; ++u)
        asm volatile("" : "+v"(r0[u]), "+v"(r1[u]), "+v"(r2[u]), "+v"(r3[u]));

    const float dwv = act ? dw[l] : 0.0f;
    const float* zp = zx4 + (size_t)b * TT * ZN;

    float h = 0.0f, c = 0.0f;
    float4 pf[8], qf[8];
    #pragma unroll
    for (int s = 0; s < 8; ++s) { pf[s] = (float4){0,0,0,0}; qf[s] = (float4){0,0,0,0}; }

    ISSUE8(pf, 0);
    for (int t = 0; t < TT; t += 16) {
        ISSUE8(qf, t + 8);
        STEPS8(pf);                      // steps t .. t+7
        ISSUE8(pf, t + 16);              // clamped (dead) on last iteration
        STEPS8(qf);                      // steps t+8 .. t+15
    }

    // out[b] = h . dense_w + dense_b  (intra-wave shuffle reduction)
    float s = act ? h * dwv : 0.0f;
    #pragma unroll
    for (int off = 32; off > 0; off >>= 1) s += __shfl_down(s, off, 64);
    if (l == 0) out[b] = s + db[0];
}

// ---------------- Fallback GEMM (round-2, slow but correct; permuted store) ------
__launch_bounds__(256, 1)
__global__ void xk_gemm_kernel(const float* __restrict__ x,
                               const float* __restrict__ K,
                               const float* __restrict__ bias,
                               float* __restrict__ zx) {
    const int b = blockIdx.x;
    const int j = threadIdx.x;

    __shared__ __align__(16) float xs[2][RPP * FF];

    float kreg[FF];
    float bj = 0.0f;
    if (j < ZN) {
        #pragma unroll
        for (int k = 0; k < FF; ++k) kreg[k] = K[k * ZN + j];
        bj = bias[j];
    }
    const int jpos = (j % UU) * 4 + (j / UU);    // permuted column position

    const float* xrow = x + (size_t)b * TT * FF;
    float* zrow = zx + (size_t)b * TT * ZN;

    ((float4*)xs[0])[threadIdx.x] = ((const float4*)xrow)[threadIdx.x];
    __syncthreads();

    const int NPASS = TT / RPP;
    for (int p = 0; p < NPASS; ++p) {
        const int cur = p & 1, nxt = cur ^ 1;
        float4 gxv;
        const bool more = (p + 1) < NPASS;
        if (more) gxv = ((const float4*)(xrow + (size_t)(p + 1) * RPP * FF))[threadIdx.x];

        if (j < ZN) {
            float acc[RPP];
            #pragma unroll
            for (int r = 0; r < RPP; ++r) acc[r] = bj;
            const float4* xb4 = (const float4*)xs[cur];
            #pragma unroll
            for (int k4 = 0; k4 < FF / 4; ++k4) {
                #pragma unroll
                for (int r = 0; r < RPP; ++r) {
                    float4 xv = xb4[r * (FF / 4) + k4];
                    acc[r] = fmaf(xv.x, kreg[4 * k4 + 0], acc[r]);
                    acc[r] = fmaf(xv.y, kreg[4 * k4 + 1], acc[r]);
                    acc[r] = fmaf(xv.z, kreg[4 * k4 + 2], acc[r]);
                    acc[r] = fmaf(xv.w, kreg[4 * k4 + 3], acc[r]);
                }
            }
            float* zpo = zrow + (size_t)p * RPP * ZN + jpos;
            #pragma unroll
            for (int r = 0; r < RPP; ++r) zpo[r * ZN] = acc[r];
        }
        if (more) ((float4*)xs[nxt])[threadIdx.x] = gxv;
        __syncthreads();
    }
}

extern "C" void kernel_launch(void* const* d_in, const int* in_sizes, int n_in,
                              void* d_out, int out_size, void* d_ws, size_t ws_size,
                              hipStream_t stream) {
    const float* x    = (const float*)d_in[0];  // [512,1024,128]
    const float* K    = (const float*)d_in[1];  // [128,200]
    const float* R    = (const float*)d_in[2];  // [50,200]
    const float* bias = (const float*)d_in[3];  // [200]
    const float* dw   = (const float*)d_in[4];  // [50,1]
    const float* db   = (const float*)d_in[5];  // [1]
    float* out = (float*)d_out;                 // [512,1]

    const size_t zx_bytes = (size_t)MROWS * ZN * sizeof(float);          // 419.43 MB
    const size_t kt_elems = (size_t)NP * FF;
    const size_t kt_bytes = kt_elems * sizeof(unsigned short);

    if (ws_size >= zx_bytes + 2 * kt_bytes) {
        float* zx = (float*)d_ws;
        unsigned short* kt_hi = (unsigned short*)((char*)d_ws + zx_bytes);
        unsigned short* kt_lo = kt_hi + kt_elems;
        prep_kt_kernel<<<1, 256, 0, stream>>>(K, kt_hi, kt_lo);
        xk_mfma_kernel<<<MROWS / BM, 256, 0, stream>>>(x, kt_hi, kt_lo, bias, zx);
        lstm_scan8_kernel<<<BATCH, 64, 0, stream>>>(zx, R, dw, db, out);
    } else if (ws_size >= zx_bytes) {
        float* zx = (float*)d_ws;
        xk_gemm_kernel<<<BATCH, 256, 0, stream>>>(x, K, bias, zx);
        lstm_scan8_kernel<<<BATCH, 64, 0, stream>>>(zx, R, dw, db, out);
    }
}

// Round 9
// 828.356 us; speedup vs baseline: 1.6055x; 1.2025x over previous
//
#include <hip/hip_runtime.h>
#include <math.h>

#define BATCH 512
#define TT    1024
#define FF    128
#define UU    50
#define ZN    200          // 4*UU
#define NP    208          // padded N (13 * 16)
#define NT    13           // N tiles of 16
#define MROWS (BATCH * TT) // 524288
#define BM    128          // rows per GEMM block
#define RPP   8            // rows per pass in fallback GEMM
#define ESTRIDE 212        // GEMM epilogue LDS row stride

typedef __attribute__((ext_vector_type(8))) short bhalf8;
typedef __attribute__((ext_vector_type(4))) short bhalf4;
typedef __attribute__((ext_vector_type(4))) float f32x4;
typedef __attribute__((ext_vector_type(2))) float f32x2;

__device__ __forceinline__ float rcp_fast(float x) {
    return __builtin_amdgcn_rcpf(x);          // v_rcp_f32 (~1ulp; fine vs 6.7e-3 thr)
}
__device__ __forceinline__ float sigmoid_fast(float x) {
    return rcp_fast(1.0f + __builtin_amdgcn_exp2f(-1.442695041f * x));
}
__device__ __forceinline__ float tanh_fast(float x) {
    float e = __builtin_amdgcn_exp2f(2.885390082f * x);   // 2^(2x*log2e)
    return fmaf(-2.0f, rcp_fast(e + 1.0f), 1.0f);
}
__device__ __forceinline__ unsigned short bf16_rtn(float x) {
    unsigned int u = __float_as_uint(x);
    unsigned int r = u + 0x7FFFu + ((u >> 16) & 1u);
    return (unsigned short)(r >> 16);
}
__device__ __forceinline__ float bf16_f32(unsigned short h) {
    return __uint_as_float(((unsigned int)h) << 16);
}

// ---------------- Prep: Kt_hi/Kt_lo[NP][FF] bf16 (transposed, hi/lo split) -------
__global__ void prep_kt_kernel(const float* __restrict__ K,
                               unsigned short* __restrict__ kt_hi,
                               unsigned short* __restrict__ kt_lo) {
    const int c = threadIdx.x;
    if (c >= NP) return;
    for (int k = 0; k < FF; ++k) {
        float v = (c < ZN) ? K[k * ZN + c] : 0.0f;
        unsigned short h = bf16_rtn(v);
        float lo = v - bf16_f32(h);
        kt_hi[c * FF + k] = h;
        kt_lo[c * FF + k] = bf16_rtn(lo);
    }
}

// ---------------- Kernel A: zx = x @ K + bias via bf16x2-split MFMA --------------
// (unchanged from round 8 — verified; permuted epilogue zx4[m][u*4+g])
__launch_bounds__(256, 2)
__global__ void xk_mfma_kernel(const float* __restrict__ x,
                               const unsigned short* __restrict__ kt_hi,
                               const unsigned short* __restrict__ kt_lo,
                               const float* __restrict__ bias,
                               float* __restrict__ zx) {
    __shared__ __align__(16) char xlds[2 * BM * FF * 2];   // 64 KiB; reused by epilogue

    const int tid = threadIdx.x;
    const size_t rowbase = (size_t)blockIdx.x * BM;
    const float* xb = x + rowbase * FF;

    const float4* gx = (const float4*)xb;
    #pragma unroll
    for (int i = 0; i < 16; ++i) {
        float4 v = gx[tid + 256 * i];
        const int fidx = (tid + 256 * i) * 4;
        const int row = fidx >> 7;
        const int col = fidx & 127;
        unsigned short h0 = bf16_rtn(v.x), h1 = bf16_rtn(v.y),
                       h2 = bf16_rtn(v.z), h3 = bf16_rtn(v.w);
        bhalf4 hv = { (short)h0, (short)h1, (short)h2, (short)h3 };
        bhalf4 lv = { (short)bf16_rtn(v.x - bf16_f32(h0)),
                      (short)bf16_rtn(v.y - bf16_f32(h1)),
                      (short)bf16_rtn(v.z - bf16_f32(h2)),
                      (short)bf16_rtn(v.w - bf16_f32(h3)) };
        const unsigned byte = (unsigned)((row << 8) + (col << 1)) ^ (((unsigned)row & 7u) << 4);
        *(bhalf4*)(xlds + byte)         = hv;
        *(bhalf4*)(xlds + 32768 + byte) = lv;
    }
    __syncthreads();

    const int w = tid >> 6, l = tid & 63;
    const int lrow = l & 15;
    const int lk   = (l >> 4) << 3;

    float bv[NT];
    #pragma unroll
    for (int nt = 0; nt < NT; ++nt) {
        const int cidx = nt * 16 + lrow;
        bv[nt] = (cidx < ZN) ? bias[cidx] : 0.0f;
    }

    f32x4 acc0[NT], acc1[NT];
    #pragma unroll
    for (int nt = 0; nt < NT; ++nt) { acc0[nt] = (f32x4)0.0f; acc1[nt] = (f32x4)0.0f; }

    #pragma unroll
    for (int ks = 0; ks < 4; ++ks) {
        const int kbyte = (ks * 32 + lk) * 2;
        const int row0 = (w << 5) + lrow;
        const int row1 = row0 + 16;
        const unsigned b0 = (unsigned)((row0 << 8) + kbyte) ^ (((unsigned)row0 & 7u) << 4);
        const unsigned b1 = (unsigned)((row1 << 8) + kbyte) ^ (((unsigned)row1 & 7u) << 4);
        bhalf8 aH0 = *(const bhalf8*)(xlds + b0);
        bhalf8 aL0 = *(const bhalf8*)(xlds + 32768 + b0);
        bhalf8 aH1 = *(const bhalf8*)(xlds + b1);
        bhalf8 aL1 = *(const bhalf8*)(xlds + 32768 + b1);
        #pragma unroll
        for (int nt = 0; nt < NT; ++nt) {
            const int col = nt * 16 + lrow;
            const size_t koff = ((size_t)col << 7) + (size_t)(ks * 32 + lk);
            bhalf8 bH = *(const bhalf8*)(kt_hi + koff);
            bhalf8 bL = *(const bhalf8*)(kt_lo + koff);
            acc0[nt] = __builtin_amdgcn_mfma_f32_16x16x32_bf16(aH0, bH, acc0[nt], 0, 0, 0);
            acc0[nt] = __builtin_amdgcn_mfma_f32_16x16x32_bf16(aH0, bL, acc0[nt], 0, 0, 0);
            acc0[nt] = __builtin_amdgcn_mfma_f32_16x16x32_bf16(aL0, bH, acc0[nt], 0, 0, 0);
            acc1[nt] = __builtin_amdgcn_mfma_f32_16x16x32_bf16(aH1, bH, acc1[nt], 0, 0, 0);
            acc1[nt] = __builtin_amdgcn_mfma_f32_16x16x32_bf16(aH1, bL, acc1[nt], 0, 0, 0);
            acc1[nt] = __builtin_amdgcn_mfma_f32_16x16x32_bf16(aL1, bH, acc1[nt], 0, 0, 0);
        }
    }

    float* elds = (float*)xlds;
    const int rsub = (l >> 4) << 2;
    #pragma unroll
    for (int half = 0; half < 2; ++half) {
        __syncthreads();
        if ((w >> 1) == half) {
            const int lr = (w & 1) * 32;
            #pragma unroll
            for (int nt = 0; nt < NT; ++nt) {
                #pragma unroll
                for (int r = 0; r < 4; ++r) {
                    elds[(lr + rsub + r) * ESTRIDE + nt * 16 + lrow]      = acc0[nt][r] + bv[nt];
                    elds[(lr + 16 + rsub + r) * ESTRIDE + nt * 16 + lrow] = acc1[nt][r] + bv[nt];
                }
            }
        }
        __syncthreads();
        // permuted copy: gather the 4 gate cols of unit u -> one coalesced float4
        for (int f = tid; f < 64 * 50; f += 256) {
            const int row = f / 50;
            const int u = f - row * 50;
            float4 v;
            v.x = elds[row * ESTRIDE + u];          // i  (col u)
            v.y = elds[row * ESTRIDE + u + 50];     // f
            v.z = elds[row * ESTRIDE + u + 100];    // g
            v.w = elds[row * ESTRIDE + u + 150];    // o
            *(float4*)&zx[(rowbase + half * 64 + row) * ZN + u * 4] = v;
        }
    }
}

// ---------------- Kernel B: scan9 — LDS h-broadcast + packed fp32 FMA ------------
// 1 wave/batch, zero barriers. r8's 50 readlanes/step (SGPR-write->VALU-read
// hazards ~1000cyc/step stall) replaced by uniform-address LDS broadcast reads
// (12 b128 + 1 b64, conflict-free, LDS pipe). K-dim paired into f32x2 so
// h@R becomes 100 v_pk_fma_f32 (both halves = partial sums of the SAME output;
// no op_sel needed). Gates branch-free on all 64 lanes (z=0 -> h stays 0).
#define ISSUE8(DST, T0) do {                                                  \
    _Pragma("unroll")                                                         \
    for (int s = 0; s < 8; ++s) {                                             \
        int tt = (T0) + s; if (tt > TT - 1) tt = TT - 1;                      \
        if (act) DST[s] = *(const float4*)&zp[(size_t)tt * ZN + l * 4];       \
    }                                                                         \
} while (0)

#define STEP9(V) do {                                                         \
    f32x2 acc0 = {(V).x, 0.f}, acc1 = {(V).y, 0.f};                           \
    f32x2 acc2 = {(V).z, 0.f}, acc3 = {(V).w, 0.f};                           \
    _Pragma("unroll")                                                         \
    for (int k4 = 0; k4 < 12; ++k4) {                                         \
        float4 hv = ((const float4*)hbuf)[k4];     /* uniform addr broadcast */ \
        f32x2 hp0 = {hv.x, hv.y}, hp1 = {hv.z, hv.w};                         \
        acc0 = __builtin_elementwise_fma(hp0, rr0[2 * k4], acc0);             \
        acc1 = __builtin_elementwise_fma(hp0, rr1[2 * k4], acc1);             \
        acc2 = __builtin_elementwise_fma(hp0, rr2[2 * k4], acc2);             \
        acc3 = __builtin_elementwise_fma(hp0, rr3[2 * k4], acc3);             \
        acc0 = __builtin_elementwise_fma(hp1, rr0[2 * k4 + 1], acc0);         \
        acc1 = __builtin_elementwise_fma(hp1, rr1[2 * k4 + 1], acc1);         \
        acc2 = __builtin_elementwise_fma(hp1, rr2[2 * k4 + 1], acc2);         \
        acc3 = __builtin_elementwise_fma(hp1, rr3[2 * k4 + 1], acc3);         \
    }                                                                         \
    {                                                                         \
        f32x2 hp = ((const f32x2*)hbuf)[24];       /* h[48], h[49] */         \
        acc0 = __builtin_elementwise_fma(hp, rr0[24], acc0);                  \
        acc1 = __builtin_elementwise_fma(hp, rr1[24], acc1);                  \
        acc2 = __builtin_elementwise_fma(hp, rr2[24], acc2);                  \
        acc3 = __builtin_elementwise_fma(hp, rr3[24], acc3);                  \
    }                                                                         \
    float zi = acc0.x + acc0.y, zf = acc1.x + acc1.y;                         \
    float zg = acc2.x + acc2.y, zo = acc3.x + acc3.y;                         \
    float gi = sigmoid_fast(zi), gf = sigmoid_fast(zf);                       \
    float go = sigmoid_fast(zo), gg = tanh_fast(zg);                          \
    c = gf * c + gi * gg;                                                     \
    h = go * tanh_fast(c);                                                    \
    hbuf[l] = h;                                   /* lanes>=50 write 0 */    \
} while (0)

#define STEPS8(SRC) do {                                                      \
    STEP9(SRC[0]); STEP9(SRC[1]); STEP9(SRC[2]); STEP9(SRC[3]);               \
    STEP9(SRC[4]); STEP9(SRC[5]); STEP9(SRC[6]); STEP9(SRC[7]);               \
} while (0)

__launch_bounds__(64, 1)
__global__ void lstm_scan9_kernel(const float* __restrict__ zx4,
                                  const float* __restrict__ R,
                                  const float* __restrict__ dw,
                                  const float* __restrict__ db,
                                  float* __restrict__ out) {
    const int l = threadIdx.x;           // lane 0..63
    const int b = blockIdx.x;            // batch
    const bool act = (l < UU);

    __shared__ __align__(16) float hbuf[64];

    // R quadrant columns as k-pairs: rr{g}[p] = (R[2p][l+50g], R[2p+1][l+50g])
    f32x2 rr0[25], rr1[25], rr2[25], rr3[25];
    #pragma unroll
    for (int p = 0; p < 25; ++p) {
        if (act) {
            rr0[p] = (f32x2){ R[(2 * p) * ZN + l],       R[(2 * p + 1) * ZN + l] };
            rr1[p] = (f32x2){ R[(2 * p) * ZN + l + 50],  R[(2 * p + 1) * ZN + l + 50] };
            rr2[p] = (f32x2){ R[(2 * p) * ZN + l + 100], R[(2 * p + 1) * ZN + l + 100] };
            rr3[p] = (f32x2){ R[(2 * p) * ZN + l + 150], R[(2 * p + 1) * ZN + l + 150] };
        } else {
            rr0[p] = (f32x2){0.f, 0.f}; rr1[p] = (f32x2){0.f, 0.f};
            rr2[p] = (f32x2){0.f, 0.f}; rr3[p] = (f32x2){0.f, 0.f};
        }
    }
    #pragma unroll
    for (int p = 0; p < 25; ++p)
        asm volatile("" : "+v"(rr0[p]), "+v"(rr1[p]), "+v"(rr2[p]), "+v"(rr3[p]));

    const float dwv = act ? dw[l] : 0.0f;
    const float* zp = zx4 + (size_t)b * TT * ZN;

    hbuf[l] = 0.0f;                      // h(-1) = 0 (single wave: lgkm ordering)
    float h = 0.0f, c = 0.0f;

    float4 pf[8], qf[8];
    #pragma unroll
    for (int s = 0; s < 8; ++s) { pf[s] = (float4){0,0,0,0}; qf[s] = (float4){0,0,0,0}; }

    ISSUE8(pf, 0);
    for (int t = 0; t < TT; t += 16) {
        ISSUE8(qf, t + 8);
        STEPS8(pf);                      // steps t .. t+7
        ISSUE8(pf, t + 16);              // clamped (dead) on last iteration
        STEPS8(qf);                      // steps t+8 .. t+15
    }

    // out[b] = h . dense_w + dense_b  (intra-wave shuffle reduction)
    float s = act ? h * dwv : 0.0f;
    #pragma unroll
    for (int off = 32; off > 0; off >>= 1) s += __shfl_down(s, off, 64);
    if (l == 0) out[b] = s + db[0];
}

// ---------------- Fallback GEMM (round-2, slow but correct; permuted store) ------
__launch_bounds__(256, 1)
__global__ void xk_gemm_kernel(const float* __restrict__ x,
                               const float* __restrict__ K,
                               const float* __restrict__ bias,
                               float* __restrict__ zx) {
    const int b = blockIdx.x;
    const int j = threadIdx.x;

    __shared__ __align__(16) float xs[2][RPP * FF];

    float kreg[FF];
    float bj = 0.0f;
    if (j < ZN) {
        #pragma unroll
        for (int k = 0; k < FF; ++k) kreg[k] = K[k * ZN + j];
        bj = bias[j];
    }
    const int jpos = (j % UU) * 4 + (j / UU);    // permuted column position

    const float* xrow = x + (size_t)b * TT * FF;
    float* zrow = zx + (size_t)b * TT * ZN;

    ((float4*)xs[0])[threadIdx.x] = ((const float4*)xrow)[threadIdx.x];
    __syncthreads();

    const int NPASS = TT / RPP;
    for (int p = 0; p < NPASS; ++p) {
        const int cur = p & 1, nxt = cur ^ 1;
        float4 gxv;
        const bool more = (p + 1) < NPASS;
        if (more) gxv = ((const float4*)(xrow + (size_t)(p + 1) * RPP * FF))[threadIdx.x];

        if (j < ZN) {
            float acc[RPP];
            #pragma unroll
            for (int r = 0; r < RPP; ++r) acc[r] = bj;
            const float4* xb4 = (const float4*)xs[cur];
            #pragma unroll
            for (int k4 = 0; k4 < FF / 4; ++k4) {
                #pragma unroll
                for (int r = 0; r < RPP; ++r) {
                    float4 xv = xb4[r * (FF / 4) + k4];
                    acc[r] = fmaf(xv.x, kreg[4 * k4 + 0], acc[r]);
                    acc[r] = fmaf(xv.y, kreg[4 * k4 + 1], acc[r]);
                    acc[r] = fmaf(xv.z, kreg[4 * k4 + 2], acc[r]);
                    acc[r] = fmaf(xv.w, kreg[4 * k4 + 3], acc[r]);
                }
            }
            float* zpo = zrow + (size_t)p * RPP * ZN + jpos;
            #pragma unroll
            for (int r = 0; r < RPP; ++r) zpo[r * ZN] = acc[r];
        }
        if (more) ((float4*)xs[nxt])[threadIdx.x] = gxv;
        __syncthreads();
    }
}

extern "C" void kernel_launch(void* const* d_in, const int* in_sizes, int n_in,
                              void* d_out, int out_size, void* d_ws, size_t ws_size,
                              hipStream_t stream) {
    const float* x    = (const float*)d_in[0];  // [512,1024,128]
    const float* K    = (const float*)d_in[1];  // [128,200]
    const float* R    = (const float*)d_in[2];  // [50,200]
    const float* bias = (const float*)d_in[3];  // [200]
    const float* dw   = (const float*)d_in[4];  // [50,1]
    const float* db   = (const float*)d_in[5];  // [1]
    float* out = (float*)d_out;                 // [512,1]

    const size_t zx_bytes = (size_t)MROWS * ZN * sizeof(float);          // 419.43 MB
    const size_t kt_elems = (size_t)NP * FF;
    const size_t kt_bytes = kt_elems * sizeof(unsigned short);

    if (ws_size >= zx_bytes + 2 * kt_bytes) {
        float* zx = (float*)d_ws;
        unsigned short* kt_hi = (unsigned short*)((char*)d_ws + zx_bytes);
        unsigned short* kt_lo = kt_hi + kt_elems;
        prep_kt_kernel<<<1, 256, 0, stream>>>(K, kt_hi, kt_lo);
        xk_mfma_kernel<<<MROWS / BM, 256, 0, stream>>>(x, kt_hi, kt_lo, bias, zx);
        lstm_scan9_kernel<<<BATCH, 64, 0, stream>>>(zx, R, dw, db, out);
    } else if (ws_size >= zx_bytes) {
        float* zx = (float*)d_ws;
        xk_gemm_kernel<<<BATCH, 256, 0, stream>>>(x, K, bias, zx);
        lstm_scan9_kernel<<<BATCH, 64, 0, stream>>>(zx, R, dw, db, out);
    }
}

// Round 10
// 811.289 us; speedup vs baseline: 1.6393x; 1.0210x over previous
//
#include <hip/hip_runtime.h>
#include <math.h>

#define BATCH 512
#define TT    1024
#define FF    128
#define UU    50
#define ZN    200          // 4*UU
#define NP    208          // padded N (13 * 16)
#define NT    13           // N tiles of 16
#define MROWS (BATCH * TT) // 524288
#define BM    128          // rows per GEMM block
#define RPP   8            // rows per pass in fallback GEMM
#define ESTRIDE 212        // GEMM epilogue LDS row stride

typedef __attribute__((ext_vector_type(8))) short bhalf8;
typedef __attribute__((ext_vector_type(4))) short bhalf4;
typedef __attribute__((ext_vector_type(4))) float f32x4;
typedef __attribute__((ext_vector_type(2))) float f32x2;

__device__ __forceinline__ float rcp_fast(float x) {
    return __builtin_amdgcn_rcpf(x);          // v_rcp_f32 (~1ulp; fine vs 6.7e-3 thr)
}
__device__ __forceinline__ float sigmoid_fast(float x) {
    return rcp_fast(1.0f + __builtin_amdgcn_exp2f(-1.442695041f * x));
}
__device__ __forceinline__ float tanh_fast(float x) {
    float e = __builtin_amdgcn_exp2f(2.885390082f * x);   // 2^(2x*log2e)
    return fmaf(-2.0f, rcp_fast(e + 1.0f), 1.0f);
}
__device__ __forceinline__ unsigned short bf16_rtn(float x) {
    unsigned int u = __float_as_uint(x);
    unsigned int r = u + 0x7FFFu + ((u >> 16) & 1u);
    return (unsigned short)(r >> 16);
}
__device__ __forceinline__ float bf16_f32(unsigned short h) {
    return __uint_as_float(((unsigned int)h) << 16);
}

// ---------------- Prep: Kt_hi/Kt_lo[NP][FF] bf16 (transposed, hi/lo split) -------
__global__ void prep_kt_kernel(const float* __restrict__ K,
                               unsigned short* __restrict__ kt_hi,
                               unsigned short* __restrict__ kt_lo) {
    const int c = threadIdx.x;
    if (c >= NP) return;
    for (int k = 0; k < FF; ++k) {
        float v = (c < ZN) ? K[k * ZN + c] : 0.0f;
        unsigned short h = bf16_rtn(v);
        float lo = v - bf16_f32(h);
        kt_hi[c * FF + k] = h;
        kt_lo[c * FF + k] = bf16_rtn(lo);
    }
}

// ---------------- Kernel A: zx = x @ K + bias via bf16x2-split MFMA --------------
// (unchanged from round 8 — verified; permuted epilogue zx4[m][u*4+g])
__launch_bounds__(256, 2)
__global__ void xk_mfma_kernel(const float* __restrict__ x,
                               const unsigned short* __restrict__ kt_hi,
                               const unsigned short* __restrict__ kt_lo,
                               const float* __restrict__ bias,
                               float* __restrict__ zx) {
    __shared__ __align__(16) char xlds[2 * BM * FF * 2];   // 64 KiB; reused by epilogue

    const int tid = threadIdx.x;
    const size_t rowbase = (size_t)blockIdx.x * BM;
    const float* xb = x + rowbase * FF;

    const float4* gx = (const float4*)xb;
    #pragma unroll
    for (int i = 0; i < 16; ++i) {
        float4 v = gx[tid + 256 * i];
        const int fidx = (tid + 256 * i) * 4;
        const int row = fidx >> 7;
        const int col = fidx & 127;
        unsigned short h0 = bf16_rtn(v.x), h1 = bf16_rtn(v.y),
                       h2 = bf16_rtn(v.z), h3 = bf16_rtn(v.w);
        bhalf4 hv = { (short)h0, (short)h1, (short)h2, (short)h3 };
        bhalf4 lv = { (short)bf16_rtn(v.x - bf16_f32(h0)),
                      (short)bf16_rtn(v.y - bf16_f32(h1)),
                      (short)bf16_rtn(v.z - bf16_f32(h2)),
                      (short)bf16_rtn(v.w - bf16_f32(h3)) };
        const unsigned byte = (unsigned)((row << 8) + (col << 1)) ^ (((unsigned)row & 7u) << 4);
        *(bhalf4*)(xlds + byte)         = hv;
        *(bhalf4*)(xlds + 32768 + byte) = lv;
    }
    __syncthreads();

    const int w = tid >> 6, l = tid & 63;
    const int lrow = l & 15;
    const int lk   = (l >> 4) << 3;

    float bv[NT];
    #pragma unroll
    for (int nt = 0; nt < NT; ++nt) {
        const int cidx = nt * 16 + lrow;
        bv[nt] = (cidx < ZN) ? bias[cidx] : 0.0f;
    }

    f32x4 acc0[NT], acc1[NT];
    #pragma unroll
    for (int nt = 0; nt < NT; ++nt) { acc0[nt] = (f32x4)0.0f; acc1[nt] = (f32x4)0.0f; }

    #pragma unroll
    for (int ks = 0; ks < 4; ++ks) {
        const int kbyte = (ks * 32 + lk) * 2;
        const int row0 = (w << 5) + lrow;
        const int row1 = row0 + 16;
        const unsigned b0 = (unsigned)((row0 << 8) + kbyte) ^ (((unsigned)row0 & 7u) << 4);
        const unsigned b1 = (unsigned)((row1 << 8) + kbyte) ^ (((unsigned)row1 & 7u) << 4);
        bhalf8 aH0 = *(const bhalf8*)(xlds + b0);
        bhalf8 aL0 = *(const bhalf8*)(xlds + 32768 + b0);
        bhalf8 aH1 = *(const bhalf8*)(xlds + b1);
        bhalf8 aL1 = *(const bhalf8*)(xlds + 32768 + b1);
        #pragma unroll
        for (int nt = 0; nt < NT; ++nt) {
            const int col = nt * 16 + lrow;
            const size_t koff = ((size_t)col << 7) + (size_t)(ks * 32 + lk);
            bhalf8 bH = *(const bhalf8*)(kt_hi + koff);
            bhalf8 bL = *(const bhalf8*)(kt_lo + koff);
            acc0[nt] = __builtin_amdgcn_mfma_f32_16x16x32_bf16(aH0, bH, acc0[nt], 0, 0, 0);
            acc0[nt] = __builtin_amdgcn_mfma_f32_16x16x32_bf16(aH0, bL, acc0[nt], 0, 0, 0);
            acc0[nt] = __builtin_amdgcn_mfma_f32_16x16x32_bf16(aL0, bH, acc0[nt], 0, 0, 0);
            acc1[nt] = __builtin_amdgcn_mfma_f32_16x16x32_bf16(aH1, bH, acc1[nt], 0, 0, 0);
            acc1[nt] = __builtin_amdgcn_mfma_f32_16x16x32_bf16(aH1, bL, acc1[nt], 0, 0, 0);
            acc1[nt] = __builtin_amdgcn_mfma_f32_16x16x32_bf16(aL1, bH, acc1[nt], 0, 0, 0);
        }
    }

    float* elds = (float*)xlds;
    const int rsub = (l >> 4) << 2;
    #pragma unroll
    for (int half = 0; half < 2; ++half) {
        __syncthreads();
        if ((w >> 1) == half) {
            const int lr = (w & 1) * 32;
            #pragma unroll
            for (int nt = 0; nt < NT; ++nt) {
                #pragma unroll
                for (int r = 0; r < 4; ++r) {
                    elds[(lr + rsub + r) * ESTRIDE + nt * 16 + lrow]      = acc0[nt][r] + bv[nt];
                    elds[(lr + 16 + rsub + r) * ESTRIDE + nt * 16 + lrow] = acc1[nt][r] + bv[nt];
                }
            }
        }
        __syncthreads();
        // permuted copy: gather the 4 gate cols of unit u -> one coalesced float4
        for (int f = tid; f < 64 * 50; f += 256) {
            const int row = f / 50;
            const int u = f - row * 50;
            float4 v;
            v.x = elds[row * ESTRIDE + u];          // i  (col u)
            v.y = elds[row * ESTRIDE + u + 50];     // f
            v.z = elds[row * ESTRIDE + u + 100];    // g
            v.w = elds[row * ESTRIDE + u + 150];    // o
            *(float4*)&zx[(rowbase + half * 64 + row) * ZN + u * 4] = v;
        }
    }
}

// ---------------- Kernel B: scan10 — r9 structure, arch-VGPR-resident ------------
// r9's VGPR_Count=152 < the 200 regs rr needs -> ~100 rr values were demoted to
// AGPRs (arch cap 256/wave); each use cost a v_accvgpr_read (~+200 cyc/step).
// Fix: prefetch depth 8 -> 4 per buffer (frees 64 regs) so total live state
// (200 rr + 32 pf/qf + ~20 temps) fits the 256 arch-VGPR file. Depth-4 still
// covers HBM latency 3-6x (data needed 4-8 steps = 2800-5600 cyc after issue).
#define ISSUE4(DST, T0) do {                                                  \
    _Pragma("unroll")                                                         \
    for (int s = 0; s < 4; ++s) {                                             \
        int tt = (T0) + s; if (tt > TT - 1) tt = TT - 1;                      \
        if (act) DST[s] = *(const float4*)&zp[(size_t)tt * ZN + l * 4];       \
    }                                                                         \
} while (0)

#define STEP9(V) do {                                                         \
    f32x2 acc0 = {(V).x, 0.f}, acc1 = {(V).y, 0.f};                           \
    f32x2 acc2 = {(V).z, 0.f}, acc3 = {(V).w, 0.f};                           \
    _Pragma("unroll")                                                         \
    for (int k4 = 0; k4 < 12; ++k4) {                                         \
        float4 hv = ((const float4*)hbuf)[k4];     /* uniform addr broadcast */ \
        f32x2 hp0 = {hv.x, hv.y}, hp1 = {hv.z, hv.w};                         \
        acc0 = __builtin_elementwise_fma(hp0, rr0[2 * k4], acc0);             \
        acc1 = __builtin_elementwise_fma(hp0, rr1[2 * k4], acc1);             \
        acc2 = __builtin_elementwise_fma(hp0, rr2[2 * k4], acc2);             \
        acc3 = __builtin_elementwise_fma(hp0, rr3[2 * k4], acc3);             \
        acc0 = __builtin_elementwise_fma(hp1, rr0[2 * k4 + 1], acc0);         \
        acc1 = __builtin_elementwise_fma(hp1, rr1[2 * k4 + 1], acc1);         \
        acc2 = __builtin_elementwise_fma(hp1, rr2[2 * k4 + 1], acc2);         \
        acc3 = __builtin_elementwise_fma(hp1, rr3[2 * k4 + 1], acc3);         \
    }                                                                         \
    {                                                                         \
        f32x2 hp = ((const f32x2*)hbuf)[24];       /* h[48], h[49] */         \
        acc0 = __builtin_elementwise_fma(hp, rr0[24], acc0);                  \
        acc1 = __builtin_elementwise_fma(hp, rr1[24], acc1);                  \
        acc2 = __builtin_elementwise_fma(hp, rr2[24], acc2);                  \
        acc3 = __builtin_elementwise_fma(hp, rr3[24], acc3);                  \
    }                                                                         \
    float zi = acc0.x + acc0.y, zf = acc1.x + acc1.y;                         \
    float zg = acc2.x + acc2.y, zo = acc3.x + acc3.y;                         \
    float gi = sigmoid_fast(zi), gf = sigmoid_fast(zf);                       \
    float go = sigmoid_fast(zo), gg = tanh_fast(zg);                          \
    c = gf * c + gi * gg;                                                     \
    h = go * tanh_fast(c);                                                    \
    hbuf[l] = h;                                   /* lanes>=50 write 0 */    \
} while (0)

#define STEPS4(SRC) do {                                                      \
    STEP9(SRC[0]); STEP9(SRC[1]); STEP9(SRC[2]); STEP9(SRC[3]);               \
} while (0)

__launch_bounds__(64, 1)
__global__ void lstm_scan10_kernel(const float* __restrict__ zx4,
                                   const float* __restrict__ R,
                                   const float* __restrict__ dw,
                                   const float* __restrict__ db,
                                   float* __restrict__ out) {
    const int l = threadIdx.x;           // lane 0..63
    const int b = blockIdx.x;            // batch
    const bool act = (l < UU);

    __shared__ __align__(16) float hbuf[64];

    // R quadrant columns as k-pairs: rr{g}[p] = (R[2p][l+50g], R[2p+1][l+50g])
    f32x2 rr0[25], rr1[25], rr2[25], rr3[25];
    #pragma unroll
    for (int p = 0; p < 25; ++p) {
        if (act) {
            rr0[p] = (f32x2){ R[(2 * p) * ZN + l],       R[(2 * p + 1) * ZN + l] };
            rr1[p] = (f32x2){ R[(2 * p) * ZN + l + 50],  R[(2 * p + 1) * ZN + l + 50] };
            rr2[p] = (f32x2){ R[(2 * p) * ZN + l + 100], R[(2 * p + 1) * ZN + l + 100] };
            rr3[p] = (f32x2){ R[(2 * p) * ZN + l + 150], R[(2 * p + 1) * ZN + l + 150] };
        } else {
            rr0[p] = (f32x2){0.f, 0.f}; rr1[p] = (f32x2){0.f, 0.f};
            rr2[p] = (f32x2){0.f, 0.f}; rr3[p] = (f32x2){0.f, 0.f};
        }
    }
    #pragma unroll
    for (int p = 0; p < 25; ++p)
        asm volatile("" : "+v"(rr0[p]), "+v"(rr1[p]), "+v"(rr2[p]), "+v"(rr3[p]));

    const float dwv = act ? dw[l] : 0.0f;
    const float* zp = zx4 + (size_t)b * TT * ZN;

    hbuf[l] = 0.0f;                      // h(-1) = 0 (single wave: lgkm ordering)
    float h = 0.0f, c = 0.0f;

    float4 pf[4], qf[4];
    #pragma unroll
    for (int s = 0; s < 4; ++s) { pf[s] = (float4){0,0,0,0}; qf[s] = (float4){0,0,0,0}; }

    ISSUE4(pf, 0);
    for (int t = 0; t < TT; t += 8) {
        ISSUE4(qf, t + 4);
        STEPS4(pf);                      // steps t .. t+3
        ISSUE4(pf, t + 8);               // clamped (dead) on last iteration
        STEPS4(qf);                      // steps t+4 .. t+7
    }

    // out[b] = h . dense_w + dense_b  (intra-wave shuffle reduction)
    float s = act ? h * dwv : 0.0f;
    #pragma unroll
    for (int off = 32; off > 0; off >>= 1) s += __shfl_down(s, off, 64);
    if (l == 0) out[b] = s + db[0];
}

// ---------------- Fallback GEMM (round-2, slow but correct; permuted store) ------
__launch_bounds__(256, 1)
__global__ void xk_gemm_kernel(const float* __restrict__ x,
                               const float* __restrict__ K,
                               const float* __restrict__ bias,
                               float* __restrict__ zx) {
    const int b = blockIdx.x;
    const int j = threadIdx.x;

    __shared__ __align__(16) float xs[2][RPP * FF];

    float kreg[FF];
    float bj = 0.0f;
    if (j < ZN) {
        #pragma unroll
        for (int k = 0; k < FF; ++k) kreg[k] = K[k * ZN + j];
        bj = bias[j];
    }
    const int jpos = (j % UU) * 4 + (j / UU);    // permuted column position

    const float* xrow = x + (size_t)b * TT * FF;
    float* zrow = zx + (size_t)b * TT * ZN;

    ((float4*)xs[0])[threadIdx.x] = ((const float4*)xrow)[threadIdx.x];
    __syncthreads();

    const int NPASS = TT / RPP;
    for (int p = 0; p < NPASS; ++p) {
        const int cur = p & 1, nxt = cur ^ 1;
        float4 gxv;
        const bool more = (p + 1) < NPASS;
        if (more) gxv = ((const float4*)(xrow + (size_t)(p + 1) * RPP * FF))[threadIdx.x];

        if (j < ZN) {
            float acc[RPP];
            #pragma unroll
            for (int r = 0; r < RPP; ++r) acc[r] = bj;
            const float4* xb4 = (const float4*)xs[cur];
            #pragma unroll
            for (int k4 = 0; k4 < FF / 4; ++k4) {
                #pragma unroll
                for (int r = 0; r < RPP; ++r) {
                    float4 xv = xb4[r * (FF / 4) + k4];
                    acc[r] = fmaf(xv.x, kreg[4 * k4 + 0], acc[r]);
                    acc[r] = fmaf(xv.y, kreg[4 * k4 + 1], acc[r]);
                    acc[r] = fmaf(xv.z, kreg[4 * k4 + 2], acc[r]);
                    acc[r] = fmaf(xv.w, kreg[4 * k4 + 3], acc[r]);
                }
            }
            float* zpo = zrow + (size_t)p * RPP * ZN + jpos;
            #pragma unroll
            for (int r = 0; r < RPP; ++r) zpo[r * ZN] = acc[r];
        }
        if (more) ((float4*)xs[nxt])[threadIdx.x] = gxv;
        __syncthreads();
    }
}

extern "C" void kernel_launch(void* const* d_in, const int* in_sizes, int n_in,
                              void* d_out, int out_size, void* d_ws, size_t ws_size,
                              hipStream_t stream) {
    const float* x    = (const float*)d_in[0];  // [512,1024,128]
    const float* K    = (const float*)d_in[1];  // [128,200]
    const float* R    = (const float*)d_in[2];  // [50,200]
    const float* bias = (const float*)d_in[3];  // [200]
    const float* dw   = (const float*)d_in[4];  // [50,1]
    const float* db   = (const float*)d_in[5];  // [1]
    float* out = (float*)d_out;                 // [512,1]

    const size_t zx_bytes = (size_t)MROWS * ZN * sizeof(float);          // 419.43 MB
    const size_t kt_elems = (size_t)NP * FF;
    const size_t kt_bytes = kt_elems * sizeof(unsigned short);

    if (ws_size >= zx_bytes + 2 * kt_bytes) {
        float* zx = (float*)d_ws;
        unsigned short* kt_hi = (unsigned short*)((char*)d_ws + zx_bytes);
        unsigned short* kt_lo = kt_hi + kt_elems;
        prep_kt_kernel<<<1, 256, 0, stream>>>(K, kt_hi, kt_lo);
        xk_mfma_kernel<<<MROWS / BM, 256, 0, stream>>>(x, kt_hi, kt_lo, bias, zx);
        lstm_scan10_kernel<<<BATCH, 64, 0, stream>>>(zx, R, dw, db, out);
    } else if (ws_size >= zx_bytes) {
        float* zx = (float*)d_ws;
        xk_gemm_kernel<<<BATCH, 256, 0, stream>>>(x, K, bias, zx);
        lstm_scan10_kernel<<<BATCH, 64, 0, stream>>>(zx, R, dw, db, out);
    }
}